// Round 3
// baseline (2681.581 us; speedup 1.0000x reference)
//
#include <hip/hip_runtime.h>
#include <stdint.h>

#define T_LEN 2048
#define BATCH 16
#define HID   1024
#define BT    (BATCH * T_LEN)   // 32768
#define DTAIL 18                 // depths >= DTAIL go to the serial tail bucket
#define NBUCK (DTAIL + 1)

typedef short short8 __attribute__((ext_vector_type(8)));
typedef float f32x4  __attribute__((ext_vector_type(4)));
typedef unsigned short u16;
typedef unsigned int   u32;

__device__ __forceinline__ u16 f2bf(float f) {          // RNE f32->bf16
  u32 u = __builtin_bit_cast(u32, f);
  u = (u + 0x7fffu + ((u >> 16) & 1u)) >> 16;
  return (u16)u;
}
__device__ __forceinline__ float bf2f(u16 h) {
  u32 u = ((u32)h) << 16;
  return __builtin_bit_cast(float, u);
}

// ---------- small utility kernels ----------
__global__ void k_dbg(float* o, float v) { o[0] = v; }

__global__ void k_cvt(const float* __restrict__ s, u16* __restrict__ d, int n8) {
  int i = blockIdx.x * blockDim.x + threadIdx.x;
  if (i >= n8) return;
  const float4* sp = (const float4*)s;
  float4 a = sp[i * 2], b = sp[i * 2 + 1];
  union { u16 h[8]; uint4 v; } o;
  o.h[0] = f2bf(a.x); o.h[1] = f2bf(a.y); o.h[2] = f2bf(a.z); o.h[3] = f2bf(a.w);
  o.h[4] = f2bf(b.x); o.h[5] = f2bf(b.y); o.h[6] = f2bf(b.z); o.h[7] = f2bf(b.w);
  ((uint4*)d)[i] = o.v;
}

// dst[i][h] = src[h][i], f32 -> bf16, 1024x1024
__global__ void k_tr(const float* __restrict__ src, u16* __restrict__ dst) {
  __shared__ float tile[32][33];
  int bx = blockIdx.x * 32, by = blockIdx.y * 32;
  int tx = threadIdx.x, ty = threadIdx.y;   // 32 x 8
#pragma unroll
  for (int j = 0; j < 4; ++j)
    tile[ty + j * 8][tx] = src[(size_t)(by + ty + j * 8) * HID + bx + tx];
  __syncthreads();
#pragma unroll
  for (int j = 0; j < 4; ++j)
    dst[(size_t)(bx + ty + j * 8) * HID + by + tx] = f2bf(tile[tx][ty + j * 8]);
}

// out[r] = sum_h W[r,h]*v[h] (+ add[r])
__global__ void k_matvec(const float* __restrict__ W, const float* __restrict__ v,
                         const float* __restrict__ add, float* __restrict__ out) {
  int r = blockIdx.x;
  float s = 0.f;
  for (int h = threadIdx.x; h < HID; h += 256)
    s += W[(size_t)r * HID + h] * v[h];
  for (int o = 32; o; o >>= 1) s += __shfl_down(s, o);
  __shared__ float ws_[4];
  if ((threadIdx.x & 63) == 0) ws_[threadIdx.x >> 6] = s;
  __syncthreads();
  if (threadIdx.x == 0) {
    s = ws_[0] + ws_[1] + ws_[2] + ws_[3];
    out[r] = s + (add ? add[r] : 0.f);
  }
}

// depth per (b,t) via parallel prefix-max of last-reset position.
// p[i] = (start ? ~d : d), d clamped to DTAIL (tail bucket). start dtype auto-detected.
__global__ __launch_bounds__(256) void k_depths(const void* startp, int* __restrict__ p,
                                                int* __restrict__ cnt) {
  __shared__ int tmax[256];
  __shared__ int lc[NBUCK];
  __shared__ int isIntSh;
  const int b = blockIdx.x;
  const int tid = threadIdx.x;
  if (tid < NBUCK) lc[tid] = 0;
  if (tid == 0) {
    const unsigned char* q = (const unsigned char*)startp;
    int nz = 0;
    for (int i = 0; i < 256; ++i) if ((i & 3) && q[i]) nz++;
    isIntSh = (nz == 0);   // bool-as-u8 would have nonzero bytes at non-word offsets
  }
  __syncthreads();
  const int isInt = isIntSh;
  int st[8], lastk[8];
  const int t0 = tid * 8;
  int last = -1;
#pragma unroll
  for (int k = 0; k < 8; ++k) {
    const int t = t0 + k;
    int s;
    if (isInt) s = ((const int*)startp)[b * T_LEN + t] != 0;
    else       s = ((const unsigned char*)startp)[b * T_LEN + t] != 0;
    st[k] = s;
    if (s || t == 0) last = t;   // t==0 counts as a reset position (h0 carry)
    lastk[k] = last;
  }
  tmax[tid] = last;
  __syncthreads();
  for (int off = 1; off < 256; off <<= 1) {   // inclusive prefix max (Hillis-Steele)
    int v = tmax[tid];
    int u = (tid >= off) ? tmax[tid - off] : -1;
    __syncthreads();
    tmax[tid] = v > u ? v : u;
    __syncthreads();
  }
  const int pre = (tid > 0) ? tmax[tid - 1] : -1;
#pragma unroll
  for (int k = 0; k < 8; ++k) {
    const int t = t0 + k;
    const int R = lastk[k] > pre ? lastk[k] : pre;   // >= 0 always
    int d = t - R;
    if (d > DTAIL) d = DTAIL;
    atomicAdd(&lc[d], 1);
    p[b * T_LEN + t] = st[k] ? ~d : d;
  }
  __syncthreads();
  if (tid < NBUCK && lc[tid]) atomicAdd(&cnt[tid], lc[tid]);
}

__global__ void k_offsets(const int* cnt, int* offs, int* cursors) {
  if (threadIdx.x == 0 && blockIdx.x == 0) {
    int s = 0;
    for (int d = 0; d < NBUCK; ++d) { offs[d] = s; cursors[d] = s; s += cnt[d]; }
  }
}

// build per-depth gather lists (wave-aggregated atomics; order-independent output)
__global__ void k_build(const int* __restrict__ p, int* cursors,
                        int* __restrict__ s0, int* __restrict__ s1, int* __restrict__ dl) {
  const int i = blockIdx.x * 256 + threadIdx.x;
  const int pv = p[i];
  const int d = pv < 0 ? ~pv : pv;
  const int isStart = pv < 0;
  const int lane = threadIdx.x & 63;
  int slot = -1;
  while (__ballot(slot < 0)) {
    unsigned long long m = __ballot(slot < 0);
    int leader = __ffsll((unsigned long long)m) - 1;
    int dle = __shfl(d, leader);
    unsigned long long grp = __ballot(slot < 0 && d == dle);
    if (slot < 0 && d == dle) {
      int base = 0;
      if (lane == leader) base = atomicAdd(&cursors[dle], (int)__popcll(grp));
      base = __shfl(base, leader);
      slot = base + (int)__popcll(grp & ((1ull << lane) - 1ull));
    }
  }
  const int b = i >> 11;
  int s;
  if (d == 0) s = isStart ? (BT + 32) : (BT + b);        // zero-row : h0 layer0 row
  else        s = i - 1;
  s0[slot] = s;
  if (d == 0) s = isStart ? (BT + 32) : (BT + 16 + b);   // zero-row : h0 layer1 row
  s1[slot] = s;
  dl[slot] = i;
}

// serial tail: items with depth >= DTAIL, processed in ascending t order (exact).
__global__ __launch_bounds__(1024) void k_tail(
    const int* __restrict__ cnt, const int* __restrict__ offs, const int* __restrict__ dstl,
    const u16* __restrict__ Uw, const float* __restrict__ bu,
    const u16* __restrict__ xp, u16* hs, float* __restrict__ hfin) {
  const int n = cnt[DTAIL];
  if (n <= 0) return;
  const int lo = offs[DTAIL];
  __shared__ int idx[4096];
  const int tid = threadIdx.x;
  const int m = n > 4096 ? 4096 : n;
  if (tid == 0) {                       // insertion sort (m is ~0-2 in practice)
    for (int i = 0; i < m; ++i) {
      int v = dstl[lo + i];
      int j = i;
      while (j > 0 && idx[j - 1] > v) { idx[j] = idx[j - 1]; --j; }
      idx[j] = v;
    }
  }
  __syncthreads();
  const int col = tid;
  for (int e = 0; e < m; ++e) {
    const int i = idx[e];
    const u16* hp = hs + (size_t)(i - 1) * HID;
    const u16* ur = Uw + (size_t)col * HID;
    float acc = 0.f;
    for (int r = 0; r < HID; ++r) acc += bf2f(ur[r]) * bf2f(hp[r]);
    const float v = acc + bu[col] + bf2f(xp[(size_t)i * HID + col]);
    const float hval = tanhf(v);
    hs[(size_t)i * HID + col] = f2bf(hval);
    if ((i & (T_LEN - 1)) == T_LEN - 1) hfin[(i >> 11) * HID + col] = hval;
    __threadfence_block();
    __syncthreads();                    // row i visible before next item may read it
  }
}

// ---------- 128^2 GEMM (kept for small M / deep scan rounds / weight combos) ----------
template <int EPI, bool GATHER>
__global__ __launch_bounds__(256) void k_gemm(
    const u16* A, const u16* __restrict__ B, void* __restrict__ C,
    const float* __restrict__ bias, int M,
    const int* __restrict__ cnt, const int* __restrict__ offs, int d,
    const int* __restrict__ srcl, const int* __restrict__ dstl,
    const u16* __restrict__ xp, const float* __restrict__ bu,
    float* __restrict__ hfin, u16* hs) {
  __shared__ u16 As[128 * 32];
  __shared__ u16 Bs[128 * 32];
  const int tid = threadIdx.x;
  const int lane = tid & 63;
  const int wv = tid >> 6;
  int Mt = M, lo = 0;
  if (GATHER) { Mt = cnt[d]; lo = offs[d]; if (Mt <= 0) return; }
  const int n0 = blockIdx.x * 128;
  const int wm = (wv >> 1) * 64;
  const int wn = (wv & 1) * 64;
  const int kcol = (lane & 3) * 8;

  for (int mb = blockIdx.y; mb * 128 < Mt; mb += gridDim.y) {
    const int m0 = mb * 128;
    const u16* aptr[2];
    const u16* bptr[2];
#pragma unroll
    for (int i = 0; i < 2; ++i) {
      const int lr = (i * 4 + wv) * 16 + (lane >> 2);
      int gr = m0 + lr;
      if (gr > Mt - 1) gr = Mt - 1;                      // tail: clamp (masked at store)
      if (GATHER) gr = srcl[lo + gr];
      aptr[i] = A + (size_t)gr * HID + kcol;
      bptr[i] = B + (size_t)(n0 + lr) * HID + kcol;
    }
    f32x4 acc[4][4] = {};
    for (int k0 = 0; k0 < HID; k0 += 32) {
      __syncthreads();
#pragma unroll
      for (int i = 0; i < 2; ++i) {
        __builtin_amdgcn_global_load_lds(
            (const __attribute__((address_space(1))) void*)(aptr[i] + k0),
            (__attribute__((address_space(3))) void*)(As + (i * 4 + wv) * 512), 16, 0, 0);
        __builtin_amdgcn_global_load_lds(
            (const __attribute__((address_space(1))) void*)(bptr[i] + k0),
            (__attribute__((address_space(3))) void*)(Bs + (i * 4 + wv) * 512), 16, 0, 0);
      }
      __syncthreads();
      short8 af[4], bf_[4];
#pragma unroll
      for (int f = 0; f < 4; ++f) {
        af[f]  = *(const short8*)(As + (wm + f * 16 + (lane & 15)) * 32 + (lane >> 4) * 8);
        bf_[f] = *(const short8*)(Bs + (wn + f * 16 + (lane & 15)) * 32 + (lane >> 4) * 8);
      }
#pragma unroll
      for (int mi = 0; mi < 4; ++mi)
#pragma unroll
        for (int ni = 0; ni < 4; ++ni)
          acc[mi][ni] = __builtin_amdgcn_mfma_f32_16x16x32_bf16(af[mi], bf_[ni], acc[mi][ni], 0, 0, 0);
    }
#pragma unroll
    for (int mi = 0; mi < 4; ++mi) {
      const int r0 = m0 + wm + mi * 16 + ((lane >> 4) << 2);
#pragma unroll
      for (int ni = 0; ni < 4; ++ni) {
        const int col = n0 + wn + ni * 16 + (lane & 15);
        float bv;
        if (EPI == 3) bv = bu[col];
        else          bv = bias ? bias[col] : 0.0f;
#pragma unroll
        for (int j = 0; j < 4; ++j) {
          const int row = r0 + j;
          if (row >= Mt) continue;
          float v = acc[mi][ni][j] + bv;
          if (EPI == 0) {
            ((u16*)C)[(size_t)row * HID + col] = f2bf(v);
          } else if (EPI == 1) {
            v = v > 0.0f ? v : 0.01f * v;
            ((u16*)C)[(size_t)row * HID + col] = f2bf(v);
          } else if (EPI == 2) {
            ((float*)C)[(size_t)row * HID + col] = v;
          } else {
            const int dsti = dstl[lo + row];
            v += bf2f(xp[(size_t)dsti * HID + col]);
            const float hval = tanhf(v);
            hs[(size_t)dsti * HID + col] = f2bf(hval);
            if ((dsti & (T_LEN - 1)) == T_LEN - 1)
              hfin[(dsti >> 11) * HID + col] = hval;
          }
        }
      }
    }
  }
}

// ---------- 256^2-tile 2-phase pipelined GEMM: C[M,1024] = A[M,1024] * B[1024,1024]^T ----------
// 8 waves (2M x 4N), BK=32, double-buffered 64KB LDS, prefetch-then-compute, one barrier/K-tile.
// gridDim.x MUST be 4 (N=1024/256). XCD-swizzled block remap (all grids %8==0).
template <int EPI, bool GATHER>
__global__ __launch_bounds__(512, 2) void k_gemm256(
    const u16* A, const u16* __restrict__ B, void* __restrict__ C,
    const float* __restrict__ bias, int M,
    const int* __restrict__ cnt, const int* __restrict__ offs, int d,
    const int* __restrict__ srcl, const int* __restrict__ dstl,
    const u16* __restrict__ xp, const float* __restrict__ bu,
    float* __restrict__ hfin, u16* hs) {
  __shared__ u16 lds[2][2 * 256 * 32];    // [dbuf][A 8192 u16 | B 8192 u16] = 64 KiB
  const int tid = threadIdx.x;
  const int lane = tid & 63;
  const int w = tid >> 6;          // wave 0..7
  const int wr = w & 1;            // M half (128 rows)
  const int wc = w >> 1;           // N quarter (64 cols)
  int Mt = M, lo = 0;
  if (GATHER) { Mt = cnt[d]; lo = offs[d]; if (Mt <= 0) return; }

  // XCD-aware bijective block remap: consecutive swz (sharing an A-panel) -> same XCD L2
  const int nid = blockIdx.y * gridDim.x + blockIdx.x;
  const int cpx = (gridDim.x * gridDim.y) >> 3;
  const int swz = (nid & 7) * cpx + (nid >> 3);
  const int n0 = (swz & 3) * 256;
  const int by0 = swz >> 2;

  // stage geometry: 4 gload_lds/thread/K-tile; wave covers 16 rows x 64B per instr
  const int srow = w * 16 + (lane >> 2);         // row within 128-row half
  const int skcol = (lane & 3) * 8;              // u16 k-offset of this lane's 16B chunk

  for (int mb = by0; mb * 256 < Mt; mb += gridDim.y) {
    const int m0 = mb * 256;
    int arow[2];
#pragma unroll
    for (int q = 0; q < 2; ++q) {
      int r = m0 + q * 128 + srow;
      if (r > Mt - 1) r = Mt - 1;                // tail: clamp (masked at store)
      if (GATHER) r = srcl[lo + r];
      arow[q] = r;
    }
    const int brow = n0 + srow;

    auto stage = [&](int p, int k0) {
#pragma unroll
      for (int q = 0; q < 2; ++q)
        __builtin_amdgcn_global_load_lds(
            (const __attribute__((address_space(1))) void*)(A + (size_t)arow[q] * HID + k0 + skcol),
            (__attribute__((address_space(3))) void*)(&lds[p][(q * 128 + w * 16) * 32]), 16, 0, 0);
#pragma unroll
      for (int q = 0; q < 2; ++q)
        __builtin_amdgcn_global_load_lds(
            (const __attribute__((address_space(1))) void*)(B + (size_t)(brow + q * 128) * HID + k0 + skcol),
            (__attribute__((address_space(3))) void*)(&lds[p][8192 + (q * 128 + w * 16) * 32]), 16, 0, 0);
    };

    f32x4 acc[8][4] = {};
    stage(0, 0);
    __syncthreads();                              // vmcnt(0) drain: tile 0 ready
    int p = 0;
    const int fr = lane & 15;
    const int ko = (lane >> 4) * 8;
    for (int t = 0; t < 32; ++t) {
      if (t < 31) stage(p ^ 1, (t + 1) * 32);     // prefetch next tile FIRST
      short8 a[8], b[4];
#pragma unroll
      for (int mi = 0; mi < 8; ++mi)
        a[mi] = *(const short8*)(&lds[p][(wr * 128 + mi * 16 + fr) * 32 + ko]);
#pragma unroll
      for (int ni = 0; ni < 4; ++ni)
        b[ni] = *(const short8*)(&lds[p][8192 + (wc * 64 + ni * 16 + fr) * 32 + ko]);
      __builtin_amdgcn_s_setprio(1);
#pragma unroll
      for (int mi = 0; mi < 8; ++mi)
#pragma unroll
        for (int ni = 0; ni < 4; ++ni)
          acc[mi][ni] = __builtin_amdgcn_mfma_f32_16x16x32_bf16(a[mi], b[ni], acc[mi][ni], 0, 0, 0);
      __builtin_amdgcn_s_setprio(0);
      __syncthreads();                            // drains vmcnt(0): next tile staged & all reads done
      p ^= 1;
    }
    // epilogue: wave tile at (m0 + wr*128, n0 + wc*64)
#pragma unroll
    for (int mi = 0; mi < 8; ++mi) {
      const int r0 = m0 + wr * 128 + mi * 16 + ((lane >> 4) << 2);
#pragma unroll
      for (int ni = 0; ni < 4; ++ni) {
        const int col = n0 + wc * 64 + ni * 16 + (lane & 15);
        float bv;
        if (EPI == 3) bv = bu[col];
        else          bv = bias ? bias[col] : 0.0f;
#pragma unroll
        for (int j = 0; j < 4; ++j) {
          const int row = r0 + j;
          if (row >= Mt) continue;
          float v = acc[mi][ni][j] + bv;
          if (EPI == 0) {
            ((u16*)C)[(size_t)row * HID + col] = f2bf(v);
          } else if (EPI == 1) {
            v = v > 0.0f ? v : 0.01f * v;
            ((u16*)C)[(size_t)row * HID + col] = f2bf(v);
          } else if (EPI == 2) {
            ((float*)C)[(size_t)row * HID + col] = v;
          } else {
            const int dsti = dstl[lo + row];
            v += bf2f(xp[(size_t)dsti * HID + col]);
            const float hval = tanhf(v);
            hs[(size_t)dsti * HID + col] = f2bf(hval);
            if ((dsti & (T_LEN - 1)) == T_LEN - 1)
              hfin[(dsti >> 11) * HID + col] = hval;
          }
        }
      }
    }
  }
}

// ---------- host ----------
extern "C" void kernel_launch(void* const* d_in, const int* in_sizes, int n_in,
                              void* d_out, int out_size, void* d_ws, size_t ws_size,
                              hipStream_t stream) {
  (void)in_sizes; (void)n_in; (void)out_size;
  const float* emb   = (const float*)d_in[0];
  const void*  start = d_in[1];
  const float* h0    = (const float*)d_in[2];
  const float* Win   = (const float*)d_in[3];
  const float* b_in  = (const float*)d_in[4];
  const float* Wout  = (const float*)d_in[5];
  const float* b_out = (const float*)d_in[6];
  const float* Uh    = (const float*)d_in[7];
  const float* bUh   = (const float*)d_in[8];
  const float* Wh    = (const float*)d_in[9];
  const float* Wy    = (const float*)d_in[10];
  const float* bWy   = (const float*)d_in[11];
  const float* Wff   = (const float*)d_in[12];
  const float* bff   = (const float*)d_in[13];
  float* dout = (float*)d_out;

  char* w = (char*)d_ws;
  auto alloc = [&](size_t b) { char* r = w; w += (b + 255) & ~(size_t)255; return r; };
  u16* E     = (u16*)alloc((size_t)BT * HID * 2);          // emb bf16, later reused as layer_in
  u16* X1    = (u16*)alloc((size_t)BT * HID * 2);          // xp
  u16* HS    = (u16*)alloc((size_t)(BT + 33) * HID * 2);   // hs + 32 h0 rows + zero row
  u16* W0b   = (u16*)alloc((size_t)HID * HID * 2);
  u16* Wc0b  = (u16*)alloc((size_t)HID * HID * 2);
  u16* Wc1b  = (u16*)alloc((size_t)HID * HID * 2);
  u16* Wh1b  = (u16*)alloc((size_t)HID * HID * 2);
  u16* Woutb = (u16*)alloc((size_t)HID * HID * 2);
  u16* Uhb   = (u16*)alloc((size_t)2 * HID * HID * 2);
  u16* Wh0b  = (u16*)alloc((size_t)HID * HID * 2);
  u16* Wff0b = (u16*)alloc((size_t)HID * HID * 2);
  u16* Wff1b = (u16*)alloc((size_t)HID * HID * 2);
  u16* WinT  = (u16*)alloc((size_t)HID * HID * 2);
  u16* Wy0T  = (u16*)alloc((size_t)HID * HID * 2);
  u16* Wy1T  = (u16*)alloc((size_t)HID * HID * 2);
  float* bias0 = (float*)alloc(HID * 4);
  float* bc0   = (float*)alloc(HID * 4);
  float* bc1   = (float*)alloc(HID * 4);
  int* pArr = (int*)alloc(BT * 4);
  int* src0 = (int*)alloc(BT * 4);
  int* src1 = (int*)alloc(BT * 4);
  int* dstl = (int*)alloc(BT * 4);
  int* cnts = (int*)alloc(64 * 4);
  int* offs = (int*)alloc(64 * 4);
  int* curs = (int*)alloc(64 * 4);

  if ((size_t)(w - (char*)d_ws) > ws_size) {   // diagnostic: report ws_size and bail
    k_dbg<<<1, 1, 0, stream>>>(dout, (float)ws_size);
    return;
  }

  hipMemsetAsync(cnts, 0, NBUCK * 4, stream);
  hipMemsetAsync(HS + (size_t)(BT + 32) * HID, 0, HID * 2, stream);   // zero row

  // converts (f32 -> bf16)
  k_cvt<<<(BT * HID / 8 + 255) / 256, 256, 0, stream>>>(emb, E, BT * HID / 8);
  k_cvt<<<1024, 256, 0, stream>>>(Uh, Uhb, 2 * HID * HID / 8);
  k_cvt<<<512, 256, 0, stream>>>(Wh,             Wh0b,  HID * HID / 8);
  k_cvt<<<512, 256, 0, stream>>>(Wh + HID * HID, Wh1b,  HID * HID / 8);
  k_cvt<<<512, 256, 0, stream>>>(Wff,             Wff0b, HID * HID / 8);
  k_cvt<<<512, 256, 0, stream>>>(Wff + HID * HID, Wff1b, HID * HID / 8);
  k_cvt<<<512, 256, 0, stream>>>(Wout, Woutb, HID * HID / 8);
  k_cvt<<<16, 256, 0, stream>>>(h0, HS + (size_t)BT * HID, 2 * BATCH * HID / 8);

  dim3 tb(32, 8), tg(32, 32);
  k_tr<<<tg, tb, 0, stream>>>(Win, WinT);
  k_tr<<<tg, tb, 0, stream>>>(Wy,             Wy0T);
  k_tr<<<tg, tb, 0, stream>>>(Wy + HID * HID, Wy1T);

  // folded biases: bias0 = Wh0 @ b_in ; bc_l = Wff_l @ bWy_l + bff_l
  k_matvec<<<HID, 256, 0, stream>>>(Wh, b_in, nullptr, bias0);
  k_matvec<<<HID, 256, 0, stream>>>(Wff, bWy, bff, bc0);
  k_matvec<<<HID, 256, 0, stream>>>(Wff + HID * HID, bWy + HID, bff + HID, bc1);

  // depth lists
  k_depths<<<BATCH, 256, 0, stream>>>(start, pArr, cnts);
  k_offsets<<<1, 64, 0, stream>>>(cnts, offs, curs);
  k_build<<<BT / 256, 256, 0, stream>>>(pArr, curs, src0, src1, dstl);

  // combined weights: W0 = Wh0@Win, Wc_l = Wff_l@Wy_l  (128^2 kernel, M=1024)
  k_gemm<0, false><<<dim3(8, 8), 256, 0, stream>>>(Wh0b, WinT, W0b, nullptr, HID,
      nullptr, nullptr, 0, nullptr, nullptr, nullptr, nullptr, nullptr, nullptr);
  k_gemm<0, false><<<dim3(8, 8), 256, 0, stream>>>(Wff0b, Wy0T, Wc0b, nullptr, HID,
      nullptr, nullptr, 0, nullptr, nullptr, nullptr, nullptr, nullptr, nullptr);
  k_gemm<0, false><<<dim3(8, 8), 256, 0, stream>>>(Wff1b, Wy1T, Wc1b, nullptr, HID,
      nullptr, nullptr, 0, nullptr, nullptr, nullptr, nullptr, nullptr, nullptr);

  // xp0 = emb @ W0^T + bias0
  k_gemm256<0, false><<<dim3(4, 128), 512, 0, stream>>>(E, W0b, X1, bias0, BT,
      nullptr, nullptr, 0, nullptr, nullptr, nullptr, nullptr, nullptr, nullptr);

  // per-round grids: new 256^2 kernel for d<3, old 128^2 for deeper rounds
  static const int gy256[3] = {64, 32, 16};
  static const int gy[DTAIL] = {132, 66, 34, 18, 10, 6, 4, 2, 2, 2, 1, 1, 1, 1, 1, 1, 1, 1};

  // layer 0 scan (segment-parallel rounds) + exact tail
  for (int d = 0; d < 3; ++d)
    k_gemm256<3, true><<<dim3(4, gy256[d]), 512, 0, stream>>>(HS, Uhb, nullptr, nullptr, 0,
        cnts, offs, d, src0, dstl, X1, bUh, dout, HS);
  for (int d = 3; d < DTAIL; ++d)
    k_gemm<3, true><<<dim3(8, gy[d]), 256, 0, stream>>>(HS, Uhb, nullptr, nullptr, 0,
        cnts, offs, d, src0, dstl, X1, bUh, dout, HS);
  k_tail<<<1, 1024, 0, stream>>>(cnts, offs, dstl, Uhb, bUh, X1, HS, dout);

  // layer_in1 = leaky_relu(hs0 @ Wc0^T + bc0)
  k_gemm256<1, false><<<dim3(4, 128), 512, 0, stream>>>(HS, Wc0b, E, bc0, BT,
      nullptr, nullptr, 0, nullptr, nullptr, nullptr, nullptr, nullptr, nullptr);
  // xp1 = layer_in1 @ Wh1^T
  k_gemm256<0, false><<<dim3(4, 128), 512, 0, stream>>>(E, Wh1b, X1, nullptr, BT,
      nullptr, nullptr, 0, nullptr, nullptr, nullptr, nullptr, nullptr, nullptr);

  // layer 1 scan + tail
  for (int d = 0; d < 3; ++d)
    k_gemm256<3, true><<<dim3(4, gy256[d]), 512, 0, stream>>>(HS, Uhb + HID * HID, nullptr, nullptr, 0,
        cnts, offs, d, src1, dstl, X1, bUh + HID, dout + BATCH * HID, HS);
  for (int d = 3; d < DTAIL; ++d)
    k_gemm<3, true><<<dim3(8, gy[d]), 256, 0, stream>>>(HS, Uhb + HID * HID, nullptr, nullptr, 0,
        cnts, offs, d, src1, dstl, X1, bUh + HID, dout + BATCH * HID, HS);
  k_tail<<<1, 1024, 0, stream>>>(cnts, offs, dstl, Uhb + HID * HID, bUh + HID, X1, HS,
                                 dout + BATCH * HID);

  // layer_in2 = leaky_relu(hs1 @ Wc1^T + bc1)
  k_gemm256<1, false><<<dim3(4, 128), 512, 0, stream>>>(HS, Wc1b, E, bc1, BT,
      nullptr, nullptr, 0, nullptr, nullptr, nullptr, nullptr, nullptr, nullptr);
  // out = layer_in2 @ Wout^T + b_out  (f32, after the 2*16*1024 h_finals block)
  k_gemm256<2, false><<<dim3(4, 128), 512, 0, stream>>>(E, Woutb, dout + 2 * BATCH * HID, b_out, BT,
      nullptr, nullptr, 0, nullptr, nullptr, nullptr, nullptr, nullptr, nullptr);
}

// Round 4
// 2371.052 us; speedup vs baseline: 1.1310x; 1.1310x over previous
//
#include <hip/hip_runtime.h>
#include <stdint.h>

#define T_LEN 2048
#define BATCH 16
#define HID   1024
#define BT    (BATCH * T_LEN)   // 32768
#define DTAIL 18                 // depths >= DTAIL go to the serial tail bucket
#define NBUCK (DTAIL + 1)

typedef short short8 __attribute__((ext_vector_type(8)));
typedef float f32x4  __attribute__((ext_vector_type(4)));
typedef unsigned short u16;
typedef unsigned int   u32;

__device__ __forceinline__ u16 f2bf(float f) {          // RNE f32->bf16
  u32 u = __builtin_bit_cast(u32, f);
  u = (u + 0x7fffu + ((u >> 16) & 1u)) >> 16;
  return (u16)u;
}
__device__ __forceinline__ float bf2f(u16 h) {
  u32 u = ((u32)h) << 16;
  return __builtin_bit_cast(float, u);
}

// ---------- small utility kernels ----------
__global__ void k_dbg(float* o, float v) { o[0] = v; }

__global__ void k_cvt(const float* __restrict__ s, u16* __restrict__ d, int n8) {
  int i = blockIdx.x * blockDim.x + threadIdx.x;
  if (i >= n8) return;
  const float4* sp = (const float4*)s;
  float4 a = sp[i * 2], b = sp[i * 2 + 1];
  union { u16 h[8]; uint4 v; } o;
  o.h[0] = f2bf(a.x); o.h[1] = f2bf(a.y); o.h[2] = f2bf(a.z); o.h[3] = f2bf(a.w);
  o.h[4] = f2bf(b.x); o.h[5] = f2bf(b.y); o.h[6] = f2bf(b.z); o.h[7] = f2bf(b.w);
  ((uint4*)d)[i] = o.v;
}

// dst[i][h] = src[h][i], f32 -> bf16, 1024x1024
__global__ void k_tr(const float* __restrict__ src, u16* __restrict__ dst) {
  __shared__ float tile[32][33];
  int bx = blockIdx.x * 32, by = blockIdx.y * 32;
  int tx = threadIdx.x, ty = threadIdx.y;   // 32 x 8
#pragma unroll
  for (int j = 0; j < 4; ++j)
    tile[ty + j * 8][tx] = src[(size_t)(by + ty + j * 8) * HID + bx + tx];
  __syncthreads();
#pragma unroll
  for (int j = 0; j < 4; ++j)
    dst[(size_t)(bx + ty + j * 8) * HID + by + tx] = f2bf(tile[tx][ty + j * 8]);
}

// out[r] = sum_h W[r,h]*v[h] (+ add[r])
__global__ void k_matvec(const float* __restrict__ W, const float* __restrict__ v,
                         const float* __restrict__ add, float* __restrict__ out) {
  int r = blockIdx.x;
  float s = 0.f;
  for (int h = threadIdx.x; h < HID; h += 256)
    s += W[(size_t)r * HID + h] * v[h];
  for (int o = 32; o; o >>= 1) s += __shfl_down(s, o);
  __shared__ float ws_[4];
  if ((threadIdx.x & 63) == 0) ws_[threadIdx.x >> 6] = s;
  __syncthreads();
  if (threadIdx.x == 0) {
    s = ws_[0] + ws_[1] + ws_[2] + ws_[3];
    out[r] = s + (add ? add[r] : 0.f);
  }
}

// depth per (b,t) via parallel prefix-max of last-reset position.
__global__ __launch_bounds__(256) void k_depths(const void* startp, int* __restrict__ p,
                                                int* __restrict__ cnt) {
  __shared__ int tmax[256];
  __shared__ int lc[NBUCK];
  __shared__ int isIntSh;
  const int b = blockIdx.x;
  const int tid = threadIdx.x;
  if (tid < NBUCK) lc[tid] = 0;
  if (tid == 0) {
    const unsigned char* q = (const unsigned char*)startp;
    int nz = 0;
    for (int i = 0; i < 256; ++i) if ((i & 3) && q[i]) nz++;
    isIntSh = (nz == 0);   // bool-as-u8 would have nonzero bytes at non-word offsets
  }
  __syncthreads();
  const int isInt = isIntSh;
  int st[8], lastk[8];
  const int t0 = tid * 8;
  int last = -1;
#pragma unroll
  for (int k = 0; k < 8; ++k) {
    const int t = t0 + k;
    int s;
    if (isInt) s = ((const int*)startp)[b * T_LEN + t] != 0;
    else       s = ((const unsigned char*)startp)[b * T_LEN + t] != 0;
    st[k] = s;
    if (s || t == 0) last = t;
    lastk[k] = last;
  }
  tmax[tid] = last;
  __syncthreads();
  for (int off = 1; off < 256; off <<= 1) {
    int v = tmax[tid];
    int u = (tid >= off) ? tmax[tid - off] : -1;
    __syncthreads();
    tmax[tid] = v > u ? v : u;
    __syncthreads();
  }
  const int pre = (tid > 0) ? tmax[tid - 1] : -1;
#pragma unroll
  for (int k = 0; k < 8; ++k) {
    const int t = t0 + k;
    const int R = lastk[k] > pre ? lastk[k] : pre;
    int d = t - R;
    if (d > DTAIL) d = DTAIL;
    atomicAdd(&lc[d], 1);
    p[b * T_LEN + t] = st[k] ? ~d : d;
  }
  __syncthreads();
  if (tid < NBUCK && lc[tid]) atomicAdd(&cnt[tid], lc[tid]);
}

__global__ void k_offsets(const int* cnt, int* offs, int* cursors) {
  if (threadIdx.x == 0 && blockIdx.x == 0) {
    int s = 0;
    for (int d = 0; d < NBUCK; ++d) { offs[d] = s; cursors[d] = s; s += cnt[d]; }
  }
}

// build per-depth gather lists (wave-aggregated atomics)
__global__ void k_build(const int* __restrict__ p, int* cursors,
                        int* __restrict__ s0, int* __restrict__ s1, int* __restrict__ dl) {
  const int i = blockIdx.x * 256 + threadIdx.x;
  const int pv = p[i];
  const int d = pv < 0 ? ~pv : pv;
  const int isStart = pv < 0;
  const int lane = threadIdx.x & 63;
  int slot = -1;
  while (__ballot(slot < 0)) {
    unsigned long long m = __ballot(slot < 0);
    int leader = __ffsll((unsigned long long)m) - 1;
    int dle = __shfl(d, leader);
    unsigned long long grp = __ballot(slot < 0 && d == dle);
    if (slot < 0 && d == dle) {
      int base = 0;
      if (lane == leader) base = atomicAdd(&cursors[dle], (int)__popcll(grp));
      base = __shfl(base, leader);
      slot = base + (int)__popcll(grp & ((1ull << lane) - 1ull));
    }
  }
  const int b = i >> 11;
  int s;
  if (d == 0) s = isStart ? (BT + 32) : (BT + b);
  else        s = i - 1;
  s0[slot] = s;
  if (d == 0) s = isStart ? (BT + 32) : (BT + 16 + b);
  s1[slot] = s;
  dl[slot] = i;
}

// serial tail: items with depth >= DTAIL, processed in ascending t order (exact).
__global__ __launch_bounds__(1024) void k_tail(
    const int* __restrict__ cnt, const int* __restrict__ offs, const int* __restrict__ dstl,
    const u16* __restrict__ Uw, const float* __restrict__ bu,
    const u16* __restrict__ xp, u16* hs, float* __restrict__ hfin) {
  const int n = cnt[DTAIL];
  if (n <= 0) return;
  const int lo = offs[DTAIL];
  __shared__ int idx[4096];
  const int tid = threadIdx.x;
  const int m = n > 4096 ? 4096 : n;
  if (tid == 0) {
    for (int i = 0; i < m; ++i) {
      int v = dstl[lo + i];
      int j = i;
      while (j > 0 && idx[j - 1] > v) { idx[j] = idx[j - 1]; --j; }
      idx[j] = v;
    }
  }
  __syncthreads();
  const int col = tid;
  for (int e = 0; e < m; ++e) {
    const int i = idx[e];
    const u16* hp = hs + (size_t)(i - 1) * HID;
    const u16* ur = Uw + (size_t)col * HID;
    float acc = 0.f;
    for (int r = 0; r < HID; ++r) acc += bf2f(ur[r]) * bf2f(hp[r]);
    const float v = acc + bu[col] + bf2f(xp[(size_t)i * HID + col]);
    const float hval = tanhf(v);
    hs[(size_t)i * HID + col] = f2bf(hval);
    if ((i & (T_LEN - 1)) == T_LEN - 1) hfin[(i >> 11) * HID + col] = hval;
    __threadfence_block();
    __syncthreads();
  }
}

// ---------- 128^2 GEMM (small M / deep scan rounds / weight combos) ----------
template <int EPI, bool GATHER>
__global__ __launch_bounds__(256) void k_gemm(
    const u16* A, const u16* __restrict__ B, void* __restrict__ C,
    const float* __restrict__ bias, int M,
    const int* __restrict__ cnt, const int* __restrict__ offs, int d,
    const int* __restrict__ srcl, const int* __restrict__ dstl,
    const u16* __restrict__ xp, const float* __restrict__ bu,
    float* __restrict__ hfin, u16* hs) {
  __shared__ u16 As[128 * 32];
  __shared__ u16 Bs[128 * 32];
  const int tid = threadIdx.x;
  const int lane = tid & 63;
  const int wv = tid >> 6;
  int Mt = M, lo = 0;
  if (GATHER) { Mt = cnt[d]; lo = offs[d]; if (Mt <= 0) return; }
  const int n0 = blockIdx.x * 128;
  const int wm = (wv >> 1) * 64;
  const int wn = (wv & 1) * 64;
  const int kcol = (lane & 3) * 8;

  for (int mb = blockIdx.y; mb * 128 < Mt; mb += gridDim.y) {
    const int m0 = mb * 128;
    const u16* aptr[2];
    const u16* bptr[2];
#pragma unroll
    for (int i = 0; i < 2; ++i) {
      const int lr = (i * 4 + wv) * 16 + (lane >> 2);
      int gr = m0 + lr;
      if (gr > Mt - 1) gr = Mt - 1;
      if (GATHER) gr = srcl[lo + gr];
      aptr[i] = A + (size_t)gr * HID + kcol;
      bptr[i] = B + (size_t)(n0 + lr) * HID + kcol;
    }
    f32x4 acc[4][4] = {};
    for (int k0 = 0; k0 < HID; k0 += 32) {
      __syncthreads();
#pragma unroll
      for (int i = 0; i < 2; ++i) {
        __builtin_amdgcn_global_load_lds(
            (const __attribute__((address_space(1))) void*)(aptr[i] + k0),
            (__attribute__((address_space(3))) void*)(As + (i * 4 + wv) * 512), 16, 0, 0);
        __builtin_amdgcn_global_load_lds(
            (const __attribute__((address_space(1))) void*)(bptr[i] + k0),
            (__attribute__((address_space(3))) void*)(Bs + (i * 4 + wv) * 512), 16, 0, 0);
      }
      __syncthreads();
      short8 af[4], bf_[4];
#pragma unroll
      for (int f = 0; f < 4; ++f) {
        af[f]  = *(const short8*)(As + (wm + f * 16 + (lane & 15)) * 32 + (lane >> 4) * 8);
        bf_[f] = *(const short8*)(Bs + (wn + f * 16 + (lane & 15)) * 32 + (lane >> 4) * 8);
      }
#pragma unroll
      for (int mi = 0; mi < 4; ++mi)
#pragma unroll
        for (int ni = 0; ni < 4; ++ni)
          acc[mi][ni] = __builtin_amdgcn_mfma_f32_16x16x32_bf16(af[mi], bf_[ni], acc[mi][ni], 0, 0, 0);
    }
#pragma unroll
    for (int mi = 0; mi < 4; ++mi) {
      const int r0 = m0 + wm + mi * 16 + ((lane >> 4) << 2);
#pragma unroll
      for (int ni = 0; ni < 4; ++ni) {
        const int col = n0 + wn + ni * 16 + (lane & 15);
        float bv;
        if (EPI == 3) bv = bu[col];
        else          bv = bias ? bias[col] : 0.0f;
#pragma unroll
        for (int j = 0; j < 4; ++j) {
          const int row = r0 + j;
          if (row >= Mt) continue;
          float v = acc[mi][ni][j] + bv;
          if (EPI == 0) {
            ((u16*)C)[(size_t)row * HID + col] = f2bf(v);
          } else if (EPI == 1) {
            v = v > 0.0f ? v : 0.01f * v;
            ((u16*)C)[(size_t)row * HID + col] = f2bf(v);
          } else if (EPI == 2) {
            ((float*)C)[(size_t)row * HID + col] = v;
          } else {
            const int dsti = dstl[lo + row];
            v += bf2f(xp[(size_t)dsti * HID + col]);
            const float hval = tanhf(v);
            hs[(size_t)dsti * HID + col] = f2bf(hval);
            if ((dsti & (T_LEN - 1)) == T_LEN - 1)
              hfin[(dsti >> 11) * HID + col] = hval;
          }
        }
      }
    }
  }
}

// ---------- 256^2 pipelined GEMM: triple-buffered LDS, counted vmcnt (T2+T3+T4+T5) ----------
// 8 waves (2M x 4N), BK=32, 3 x 32KiB LDS bufs, stage tile t+2 while computing t.
// Entry per tile: s_waitcnt vmcnt(4) (tile t+1's 4 loads stay in flight) + raw s_barrier.
// LDS bank swizzle: store global k-chunk (l&3)^((l>>3)&3), read chunk (l>>4)^((row>>1)&3).
// gridDim.x MUST be 4; grid total % 8 == 0 (bijective XCD swizzle).
template <int EPI, bool GATHER>
__global__ __launch_bounds__(512, 2) void k_pgemm(
    const u16* __restrict__ A, const u16* __restrict__ B, void* __restrict__ C,
    const float* __restrict__ bias, int M,
    const int* __restrict__ cnt, const int* __restrict__ offs, int d,
    const int* __restrict__ srcl, const int* __restrict__ dstl,
    const u16* __restrict__ xp, const float* __restrict__ bu,
    float* __restrict__ hfin, u16* hs) {
  __shared__ u16 lds3[3 * 16384];   // 96 KiB: 3 bufs x (A 256x32 | B 256x32)
  const int tid = threadIdx.x;
  const int l = tid & 63;
  const int w = tid >> 6;          // wave 0..7
  const int wr = w & 1;            // M half (128 rows)
  const int wc = w >> 1;           // N quarter (64 cols)
  int Mt = M, lo = 0;
  if (GATHER) { Mt = cnt[d]; lo = offs[d]; if (Mt <= 0) return; }

  // XCD-aware bijective remap
  const int nid = blockIdx.y * gridDim.x + blockIdx.x;
  const int cpx = (gridDim.x * gridDim.y) >> 3;
  const int swz = (nid & 7) * cpx + (nid >> 3);
  const int n0 = (swz & 3) * 256;
  const int by0 = swz >> 2;

  // staging lane geometry (each gload_lds: 16 rows x 64B contiguous LDS)
  const int srow = w * 32 + (l >> 2);               // tile row (+16 for i=1)
  const int scol = ((l & 3) ^ ((l >> 3) & 3)) * 8;  // pre-swizzled global k-chunk (u16)
  const int ldsA = w * 1024;                        // u16 offset of wave's A slab (+512 for i=1)
  // frag-read lane constants
  const int fr = l & 15;
  const int chunkP = (((l >> 4) ^ ((fr >> 1) & 3)) * 8);
  const int rdA0 = (wr * 128 + fr) * 32 + chunkP;        // + mi*512
  const int rdB0 = 8192 + (wc * 64 + fr) * 32 + chunkP;  // + ni*512

  // B staging pointers (fixed per block)
  const u16* Bp0 = B + (size_t)(n0 + srow) * HID + scol;
  const u16* Bp1 = Bp0 + (size_t)16 * HID;

  for (int mb = by0; mb * 256 < Mt; mb += gridDim.y) {
    const int m0 = mb * 256;
    const u16* Ap0;
    const u16* Ap1;
    {
      int r0 = m0 + srow, r1 = m0 + 16 + srow;
      if (r0 > Mt - 1) r0 = Mt - 1;               // tail: clamp (masked at store)
      if (r1 > Mt - 1) r1 = Mt - 1;
      if (GATHER) { r0 = srcl[lo + r0]; r1 = srcl[lo + r1]; }
      Ap0 = A + (size_t)r0 * HID + scol;
      Ap1 = A + (size_t)r1 * HID + scol;
    }

    auto STAGEA = [&](int t, int bo) {
      const int kb = t * 32;
      __builtin_amdgcn_global_load_lds(
          (const __attribute__((address_space(1))) void*)(Ap0 + kb),
          (__attribute__((address_space(3))) void*)(lds3 + bo + ldsA), 16, 0, 0);
      __builtin_amdgcn_global_load_lds(
          (const __attribute__((address_space(1))) void*)(Ap1 + kb),
          (__attribute__((address_space(3))) void*)(lds3 + bo + ldsA + 512), 16, 0, 0);
    };
    auto STAGEB = [&](int t, int bo) {
      const int kb = t * 32;
      __builtin_amdgcn_global_load_lds(
          (const __attribute__((address_space(1))) void*)(Bp0 + kb),
          (__attribute__((address_space(3))) void*)(lds3 + bo + 8192 + ldsA), 16, 0, 0);
      __builtin_amdgcn_global_load_lds(
          (const __attribute__((address_space(1))) void*)(Bp1 + kb),
          (__attribute__((address_space(3))) void*)(lds3 + bo + 8192 + ldsA + 512), 16, 0, 0);
    };

    __builtin_amdgcn_s_barrier();     // LDS reuse safe across m-iterations
    // prologue: tiles 0 and 1 (8 loads in flight)
    STAGEA(0, 0);     STAGEB(0, 0);
    STAGEA(1, 16384); STAGEB(1, 16384);

    f32x4 acc[8][4] = {};
    int bo = 0, bo2 = 32768;          // (t%3)*16384, ((t+2)%3)*16384
    for (int t = 0; t < 32; ++t) {
      if (t < 31) { asm volatile("s_waitcnt vmcnt(4)" ::: "memory"); }
      else        { asm volatile("s_waitcnt vmcnt(0)" ::: "memory"); }
      __builtin_amdgcn_s_barrier();
      __builtin_amdgcn_sched_barrier(0);
      const u16* Ab = lds3 + bo;
      short8 bfr[4], afr[4];
#pragma unroll
      for (int ni = 0; ni < 4; ++ni) bfr[ni] = *(const short8*)(Ab + rdB0 + ni * 512);
#pragma unroll
      for (int mi = 0; mi < 4; ++mi) afr[mi] = *(const short8*)(Ab + rdA0 + mi * 512);
      if (t < 30) STAGEA(t + 2, bo2);
      __builtin_amdgcn_s_setprio(1);
#pragma unroll
      for (int mi = 0; mi < 4; ++mi)
#pragma unroll
        for (int ni = 0; ni < 4; ++ni)
          acc[mi][ni] = __builtin_amdgcn_mfma_f32_16x16x32_bf16(afr[mi], bfr[ni], acc[mi][ni], 0, 0, 0);
      __builtin_amdgcn_s_setprio(0);
#pragma unroll
      for (int mi = 0; mi < 4; ++mi) afr[mi] = *(const short8*)(Ab + rdA0 + (mi + 4) * 512);
      if (t < 30) STAGEB(t + 2, bo2);
      __builtin_amdgcn_s_setprio(1);
#pragma unroll
      for (int mi = 0; mi < 4; ++mi)
#pragma unroll
        for (int ni = 0; ni < 4; ++ni)
          acc[mi + 4][ni] = __builtin_amdgcn_mfma_f32_16x16x32_bf16(afr[mi], bfr[ni], acc[mi + 4][ni], 0, 0, 0);
      __builtin_amdgcn_s_setprio(0);
      bo += 16384;  if (bo == 49152)  bo = 0;
      bo2 += 16384; if (bo2 == 49152) bo2 = 0;
    }

    // epilogue: wave tile at (m0 + wr*128, n0 + wc*64)
#pragma unroll
    for (int mi = 0; mi < 8; ++mi) {
      const int r0 = m0 + wr * 128 + mi * 16 + ((l >> 4) << 2);
#pragma unroll
      for (int ni = 0; ni < 4; ++ni) {
        const int col = n0 + wc * 64 + ni * 16 + fr;
        float bv;
        if (EPI == 3) bv = bu[col];
        else          bv = bias ? bias[col] : 0.0f;
#pragma unroll
        for (int j = 0; j < 4; ++j) {
          const int row = r0 + j;
          if (row >= Mt) continue;
          float v = acc[mi][ni][j] + bv;
          if (EPI == 0) {
            ((u16*)C)[(size_t)row * HID + col] = f2bf(v);
          } else if (EPI == 1) {
            v = v > 0.0f ? v : 0.01f * v;
            ((u16*)C)[(size_t)row * HID + col] = f2bf(v);
          } else if (EPI == 2) {
            ((float*)C)[(size_t)row * HID + col] = v;
          } else {
            const int dsti = dstl[lo + row];
            v += bf2f(xp[(size_t)dsti * HID + col]);
            const float hval = tanhf(v);
            hs[(size_t)dsti * HID + col] = f2bf(hval);
            if ((dsti & (T_LEN - 1)) == T_LEN - 1)
              hfin[(dsti >> 11) * HID + col] = hval;
          }
        }
      }
    }
  }
}

// ---------- host ----------
extern "C" void kernel_launch(void* const* d_in, const int* in_sizes, int n_in,
                              void* d_out, int out_size, void* d_ws, size_t ws_size,
                              hipStream_t stream) {
  (void)in_sizes; (void)n_in; (void)out_size;
  const float* emb   = (const float*)d_in[0];
  const void*  start = d_in[1];
  const float* h0    = (const float*)d_in[2];
  const float* Win   = (const float*)d_in[3];
  const float* b_in  = (const float*)d_in[4];
  const float* Wout  = (const float*)d_in[5];
  const float* b_out = (const float*)d_in[6];
  const float* Uh    = (const float*)d_in[7];
  const float* bUh   = (const float*)d_in[8];
  const float* Wh    = (const float*)d_in[9];
  const float* Wy    = (const float*)d_in[10];
  const float* bWy   = (const float*)d_in[11];
  const float* Wff   = (const float*)d_in[12];
  const float* bff   = (const float*)d_in[13];
  float* dout = (float*)d_out;

  char* w = (char*)d_ws;
  auto alloc = [&](size_t b) { char* r = w; w += (b + 255) & ~(size_t)255; return r; };
  u16* E     = (u16*)alloc((size_t)BT * HID * 2);
  u16* X1    = (u16*)alloc((size_t)BT * HID * 2);
  u16* HS    = (u16*)alloc((size_t)(BT + 33) * HID * 2);
  u16* W0b   = (u16*)alloc((size_t)HID * HID * 2);
  u16* Wc0b  = (u16*)alloc((size_t)HID * HID * 2);
  u16* Wc1b  = (u16*)alloc((size_t)HID * HID * 2);
  u16* Wh1b  = (u16*)alloc((size_t)HID * HID * 2);
  u16* Woutb = (u16*)alloc((size_t)HID * HID * 2);
  u16* Uhb   = (u16*)alloc((size_t)2 * HID * HID * 2);
  u16* Wh0b  = (u16*)alloc((size_t)HID * HID * 2);
  u16* Wff0b = (u16*)alloc((size_t)HID * HID * 2);
  u16* Wff1b = (u16*)alloc((size_t)HID * HID * 2);
  u16* WinT  = (u16*)alloc((size_t)HID * HID * 2);
  u16* Wy0T  = (u16*)alloc((size_t)HID * HID * 2);
  u16* Wy1T  = (u16*)alloc((size_t)HID * HID * 2);
  float* bias0 = (float*)alloc(HID * 4);
  float* bc0   = (float*)alloc(HID * 4);
  float* bc1   = (float*)alloc(HID * 4);
  int* pArr = (int*)alloc(BT * 4);
  int* src0 = (int*)alloc(BT * 4);
  int* src1 = (int*)alloc(BT * 4);
  int* dstl = (int*)alloc(BT * 4);
  int* cnts = (int*)alloc(64 * 4);
  int* offs = (int*)alloc(64 * 4);
  int* curs = (int*)alloc(64 * 4);

  if ((size_t)(w - (char*)d_ws) > ws_size) {
    k_dbg<<<1, 1, 0, stream>>>(dout, (float)ws_size);
    return;
  }

  hipMemsetAsync(cnts, 0, NBUCK * 4, stream);
  hipMemsetAsync(HS + (size_t)(BT + 32) * HID, 0, HID * 2, stream);

  // converts (f32 -> bf16)
  k_cvt<<<(BT * HID / 8 + 255) / 256, 256, 0, stream>>>(emb, E, BT * HID / 8);
  k_cvt<<<1024, 256, 0, stream>>>(Uh, Uhb, 2 * HID * HID / 8);
  k_cvt<<<512, 256, 0, stream>>>(Wh,             Wh0b,  HID * HID / 8);
  k_cvt<<<512, 256, 0, stream>>>(Wh + HID * HID, Wh1b,  HID * HID / 8);
  k_cvt<<<512, 256, 0, stream>>>(Wff,             Wff0b, HID * HID / 8);
  k_cvt<<<512, 256, 0, stream>>>(Wff + HID * HID, Wff1b, HID * HID / 8);
  k_cvt<<<512, 256, 0, stream>>>(Wout, Woutb, HID * HID / 8);
  k_cvt<<<16, 256, 0, stream>>>(h0, HS + (size_t)BT * HID, 2 * BATCH * HID / 8);

  dim3 tb(32, 8), tg(32, 32);
  k_tr<<<tg, tb, 0, stream>>>(Win, WinT);
  k_tr<<<tg, tb, 0, stream>>>(Wy,             Wy0T);
  k_tr<<<tg, tb, 0, stream>>>(Wy + HID * HID, Wy1T);

  // folded biases
  k_matvec<<<HID, 256, 0, stream>>>(Wh, b_in, nullptr, bias0);
  k_matvec<<<HID, 256, 0, stream>>>(Wff, bWy, bff, bc0);
  k_matvec<<<HID, 256, 0, stream>>>(Wff + HID * HID, bWy + HID, bff + HID, bc1);

  // depth lists
  k_depths<<<BATCH, 256, 0, stream>>>(start, pArr, cnts);
  k_offsets<<<1, 64, 0, stream>>>(cnts, offs, curs);
  k_build<<<BT / 256, 256, 0, stream>>>(pArr, curs, src0, src1, dstl);

  // combined weights: W0 = Wh0@Win, Wc_l = Wff_l@Wy_l  (128^2 kernel, M=1024)
  k_gemm<0, false><<<dim3(8, 8), 256, 0, stream>>>(Wh0b, WinT, W0b, nullptr, HID,
      nullptr, nullptr, 0, nullptr, nullptr, nullptr, nullptr, nullptr, nullptr);
  k_gemm<0, false><<<dim3(8, 8), 256, 0, stream>>>(Wff0b, Wy0T, Wc0b, nullptr, HID,
      nullptr, nullptr, 0, nullptr, nullptr, nullptr, nullptr, nullptr, nullptr);
  k_gemm<0, false><<<dim3(8, 8), 256, 0, stream>>>(Wff1b, Wy1T, Wc1b, nullptr, HID,
      nullptr, nullptr, 0, nullptr, nullptr, nullptr, nullptr, nullptr, nullptr);

  // xp0 = emb @ W0^T + bias0
  k_pgemm<0, false><<<dim3(4, 128), 512, 0, stream>>>(E, W0b, X1, bias0, BT,
      nullptr, nullptr, 0, nullptr, nullptr, nullptr, nullptr, nullptr, nullptr);

  // scan rounds: pipelined 256^2 for d<2, 128^2 for deeper (grid-stride covers overflow)
  static const int gy[DTAIL] = {132, 66, 34, 18, 10, 6, 4, 2, 2, 2, 1, 1, 1, 1, 1, 1, 1, 1};

  // layer 0 scan + exact tail
  k_pgemm<3, true><<<dim3(4, 66), 512, 0, stream>>>(HS, Uhb, nullptr, nullptr, 0,
      cnts, offs, 0, src0, dstl, X1, bUh, dout, HS);
  k_pgemm<3, true><<<dim3(4, 34), 512, 0, stream>>>(HS, Uhb, nullptr, nullptr, 0,
      cnts, offs, 1, src0, dstl, X1, bUh, dout, HS);
  for (int d = 2; d < DTAIL; ++d)
    k_gemm<3, true><<<dim3(8, gy[d]), 256, 0, stream>>>(HS, Uhb, nullptr, nullptr, 0,
        cnts, offs, d, src0, dstl, X1, bUh, dout, HS);
  k_tail<<<1, 1024, 0, stream>>>(cnts, offs, dstl, Uhb, bUh, X1, HS, dout);

  // layer_in1 = leaky_relu(hs0 @ Wc0^T + bc0)
  k_pgemm<1, false><<<dim3(4, 128), 512, 0, stream>>>(HS, Wc0b, E, bc0, BT,
      nullptr, nullptr, 0, nullptr, nullptr, nullptr, nullptr, nullptr, nullptr);
  // xp1 = layer_in1 @ Wh1^T
  k_pgemm<0, false><<<dim3(4, 128), 512, 0, stream>>>(E, Wh1b, X1, nullptr, BT,
      nullptr, nullptr, 0, nullptr, nullptr, nullptr, nullptr, nullptr, nullptr);

  // layer 1 scan + tail
  k_pgemm<3, true><<<dim3(4, 66), 512, 0, stream>>>(HS, Uhb + HID * HID, nullptr, nullptr, 0,
      cnts, offs, 0, src1, dstl, X1, bUh + HID, dout + BATCH * HID, HS);
  k_pgemm<3, true><<<dim3(4, 34), 512, 0, stream>>>(HS, Uhb + HID * HID, nullptr, nullptr, 0,
      cnts, offs, 1, src1, dstl, X1, bUh + HID, dout + BATCH * HID, HS);
  for (int d = 2; d < DTAIL; ++d)
    k_gemm<3, true><<<dim3(8, gy[d]), 256, 0, stream>>>(HS, Uhb + HID * HID, nullptr, nullptr, 0,
        cnts, offs, d, src1, dstl, X1, bUh + HID, dout + BATCH * HID, HS);
  k_tail<<<1, 1024, 0, stream>>>(cnts, offs, dstl, Uhb + HID * HID, bUh + HID, X1, HS,
                                 dout + BATCH * HID);

  // layer_in2 = leaky_relu(hs1 @ Wc1^T + bc1)
  k_pgemm<1, false><<<dim3(4, 128), 512, 0, stream>>>(HS, Wc1b, E, bc1, BT,
      nullptr, nullptr, 0, nullptr, nullptr, nullptr, nullptr, nullptr, nullptr);
  // out = layer_in2 @ Wout^T + b_out
  k_pgemm<2, false><<<dim3(4, 128), 512, 0, stream>>>(E, Woutb, dout + 2 * BATCH * HID, b_out, BT,
      nullptr, nullptr, 0, nullptr, nullptr, nullptr, nullptr, nullptr, nullptr);
}